// Round 8
// baseline (250.167 us; speedup 1.0000x reference)
//
#include <hip/hip_runtime.h>
#include <hip/hip_bf16.h>
#include <hip/hip_fp16.h>
#include <math.h>

// ---- problem constants ----
#define NB 256      // batch
#define NN 307      // vertices
#define NBN 78592   // NB*NN
#define LL 12       // sequence length
#define DDIM 16     // model dim
#define HISW 268    // 267 history cols + 1 zero pad (for float4)
#define HIS4 67     // HISW/4
#define NBRCAP 64   // per-row neighbor capacity (mean 9.2, 64 is ~18 sigma)
#define AGRP 32     // bn rows per 256-thread attn block
#define ADTS 308    // AdT row stride (padded even for float2 alignment)
#define G1BLK 1280  // g1 sub-grid: 256 b x 5 n-tiles (blocks 0..1279)
#define ATTNBLK 2456 // attn sub-grid: NBN/AGRP (blocks 1280..3735)

// ---- workspace layout (float offsets; every segment 16B-aligned) ----
#define OFF_XTCN 0u            // 15089664 ushorts [B,N,L,D] bf16 (=7544832 floats)
#define OFF_TEK  7544832u      //    49152 floats  te@Wk+bk (inside xtcn region)
#define OFF_G1   15089664u     //   943104 floats  [B,N,L]
#define OFF_ADT  16032768u     //    94688 floats  A_dyn^T [m][308]
#define OFF_TEQ  16127456u     //    49152 floats  [B,L,16]  (te@Wq+bq)/sqrt2
#define OFF_HIS  16176608u     //    82288 floats  [N,268]
#define OFF_NW   16258896u     //    19648 floats  nbr weights [N,64]
#define OFF_NIDX 16278544u     //    19648 ints    nbr indices [N,64]
#define OFF_NCNT 16298192u     //      320 ints    nbr counts
#define OFF_TEV  16298512u     //    49152 floats  te@Wv+bv
#define OFF_TEO  16347664u     //    49152 floats  te+bo

__device__ inline float4 mkf4(float a, float b, float c, float d) {
    float4 r; r.x = a; r.y = b; r.z = c; r.w = d; return r;
}
__device__ inline float bf_lo(unsigned u) { return __uint_as_float(u << 16); }
__device__ inline float bf_hi(unsigned u) { return __uint_as_float(u & 0xffff0000u); }

// ---------------------------------------------------------------------------
// K0 fused prep (block-specialized): his | TE tables | sparse A_st rows.
// ---------------------------------------------------------------------------
__global__ __launch_bounds__(256) void prep_kernel(
    const float* __restrict__ flow,
    const int* __restrict__ dayc, const int* __restrict__ weekc,
    const float* __restrict__ demb, const float* __restrict__ wemb,
    const float* __restrict__ Wq, const float* __restrict__ bq,
    const float* __restrict__ Wk, const float* __restrict__ bk,
    const float* __restrict__ Wv, const float* __restrict__ bv,
    const float* __restrict__ bo, const float* __restrict__ adj,
    float* __restrict__ his,
    float* __restrict__ TEQ, float* __restrict__ TEK,
    float* __restrict__ TEV, float* __restrict__ TEO,
    int* __restrict__ ncnt, int* __restrict__ nidx, float* __restrict__ nw) {
    __shared__ float sTE[16][16];
    int bx = blockIdx.x, t = threadIdx.x;
    if (bx < 322) {
        int e = bx * 256 + t;
        if (e < NN * HISW) {
            int n = e / HISW, j = e - n * HISW;
            float v = 0.f;
            if (j < LL) v = flow[n * LL + j];
            else if (j < 267) v = flow[((j - 11) * NN + n) * LL + 11];
            his[e] = v;
        }
    } else if (bx < 514) {
        int r = t >> 4, d = t & 15;
        int row = (bx - 322) * 16 + r;        // < 3072
        int b = row / LL, l = row - b * LL;
        int dc = dayc[b * LL + l], wc = weekc[b * LL + l];
        int i = d >> 1;
        float ang = (float)l * powf(10000.f, -0.125f * (float)i);
        float pe = (d & 1) ? cosf(ang) : sinf(ang);
        float te = demb[dc * DDIM + d] + wemb[wc * DDIM + d] + pe;
        sTE[r][d] = te;
        __syncthreads();
        float aq = bq[d], ak = bk[d], av = bv[d];
#pragma unroll
        for (int e = 0; e < 16; e++) {
            float x = sTE[r][e];
            aq += x * Wq[e * 16 + d];
            ak += x * Wk[e * 16 + d];
            av += x * Wv[e * 16 + d];
        }
        TEQ[row * 16 + d] = aq * 0.70710678118654752f;
        TEK[row * 16 + d] = ak;
        TEV[row * 16 + d] = av;
        TEO[row * 16 + d] = te + bo[d];
    } else {
        if (t < 64) {
            int n = bx - 514;
            float rs = 0.f;
            for (int m0 = 0; m0 < NN; m0 += 64) {
                int m = m0 + t;
                if (m < NN) rs += adj[n * NN + m];
            }
            for (int off = 32; off > 0; off >>= 1) rs += __shfl_xor(rs, off);
            float inv = 1.f / (rs + 1.f);
            int c = 0;
            for (int m0 = 0; m0 < NN; m0 += 64) {
                int m = m0 + t;
                float a = (m < NN) ? adj[n * NN + m] : 0.f;
                bool p = (a != 0.f);
                unsigned long long mask = __ballot(p);
                int pos = __popcll(mask & ((1ull << t) - 1ull));
                if (p && (c + pos) < NBRCAP) {
                    nidx[n * NBRCAP + c + pos] = m;
                    nw[n * NBRCAP + c + pos] = a * inv;
                }
                c += (int)__popcll(mask);
            }
            if (t == 0) ncnt[n] = c < NBRCAP ? c : NBRCAP;
        }
    }
}

// ---------------------------------------------------------------------------
// K1: A_dyn row-softmax of -dist, stored transposed AdT[m*308+n]
// ---------------------------------------------------------------------------
__global__ __launch_bounds__(256) void adyn_kernel(const float* __restrict__ his,
                                                   float* __restrict__ AdT) {
    __shared__ float4 sh[HIS4];
    __shared__ float red[256];
    int n = blockIdx.x, t = threadIdx.x;
    if (t < HIS4) sh[t] = reinterpret_cast<const float4*>(his)[n * HIS4 + t];
    __syncthreads();

    float e0 = 0.f, e1 = 0.f, lsum = 0.f;
    {
        const float4* row = reinterpret_cast<const float4*>(his) + t * HIS4;
        float4 acc = mkf4(0.f, 0.f, 0.f, 0.f);
        for (int j = 0; j < HIS4; j++) {
            float4 a = sh[j], b = row[j];
            float dx = a.x - b.x, dy = a.y - b.y, dz = a.z - b.z, dw = a.w - b.w;
            acc.x += dx * dx; acc.y += dy * dy; acc.z += dz * dz; acc.w += dw * dw;
        }
        float d2 = (acc.x + acc.y) + (acc.z + acc.w);
        e0 = __expf(-sqrtf(fmaxf(d2, 0.f)));
        lsum += e0;
    }
    int m1 = t + 256;
    if (m1 < NN) {
        const float4* row = reinterpret_cast<const float4*>(his) + m1 * HIS4;
        float4 acc = mkf4(0.f, 0.f, 0.f, 0.f);
        for (int j = 0; j < HIS4; j++) {
            float4 a = sh[j], b = row[j];
            float dx = a.x - b.x, dy = a.y - b.y, dz = a.z - b.z, dw = a.w - b.w;
            acc.x += dx * dx; acc.y += dy * dy; acc.z += dz * dz; acc.w += dw * dw;
        }
        float d2 = (acc.x + acc.y) + (acc.z + acc.w);
        e1 = __expf(-sqrtf(fmaxf(d2, 0.f)));
        lsum += e1;
    }
    red[t] = lsum;
    __syncthreads();
    for (int s = 128; s > 0; s >>= 1) {
        if (t < s) red[t] += red[t + s];
        __syncthreads();
    }
    float inv = 1.f / red[0];
    AdT[t * ADTS + n] = e0 * inv;
    if (m1 < NN) AdT[m1 * ADTS + n] = e1 * inv;
}

// ---------------------------------------------------------------------------
// K3 v11 (R8): MERGED attn + g1, block-specialized. Rationale: measured
// complementary starvation — attn VALUBusy 45% @ occ 30% (idle issue slots),
// g1 VALUBusy 8.6% @ occ 14.5% (pure latency). Co-residency lets g1's loads
// hide under attn's exp/FMA. g1 = blocks 0..1279 (early return, no barrier
// crossing; block-uniform divergence). attn = blocks 1280..3735, body
// unchanged from v10 (half2 sA, ~23KB LDS). One fewer launch gap.
// ---------------------------------------------------------------------------
__global__ __launch_bounds__(256, 8) void attn_g1_kernel(
    const float* __restrict__ flow,
    const float* __restrict__ TEQ, const float* __restrict__ TEK,
    const float* __restrict__ TEV, const float* __restrict__ TEO,
    const float* __restrict__ Wq, const float* __restrict__ Wk,
    const float* __restrict__ Wv, const float* __restrict__ Wo,
    const float* __restrict__ AdT, float* __restrict__ G1,
    unsigned short* __restrict__ xtcn) {
    __shared__ __align__(16) float sWo[256];
    __shared__ __align__(16) float sWs[48];        // wq1/sqrt2, wk1, wv1 col-sums
    __shared__ __align__(16) float sT[4][24][16];  // TEQ/TEK/TEV/TEO, 2 b's
    __shared__ __align__(8) unsigned sA[AGRP][LL][10];  // half2-packed att

    const int t = threadIdx.x;

    if (blockIdx.x < G1BLK) {
        // ---- g1 path (v5 body): blocks 0..1279, no barriers ----
        int gb = blockIdx.x;
        int b = gb / 5, nt = gb - b * 5;
        int lane = t & 63;
        int l0 = (t >> 6) * 3;
        int l0u = __builtin_amdgcn_readfirstlane(l0);
        int n = nt * 64 + lane;
        const float* fb = flow + (size_t)b * (NN * LL);
        const float* ac = AdT + nt * 64 + lane;

        float a0 = 0.f, a1 = 0.f, a2 = 0.f;
#pragma unroll 4
        for (int m = 0; m < NN; m++) {
            float w = ac[(size_t)m * ADTS];
            const float* r = fb + m * LL + l0u;
            float p0 = r[0], p1 = r[1], p2 = r[2];
            a0 += w * p0; a1 += w * p1; a2 += w * p2;
        }
        if (n < NN) {
            float* d = G1 + ((size_t)b * NN + n) * LL + l0;
            d[0] = a0; d[1] = a1; d[2] = a2;
        }
        return;
    }

    // ---- attn path (v10 body): blocks 1280..3735 ----
    const int bn0 = (blockIdx.x - G1BLK) * AGRP;
    const int b0 = bn0 / NN;
    const int rbase = b0 * LL;

    sWo[t] = Wo[t];
    if (t < 48) {
        int mat = t >> 4, d = t & 15;
        const float* W = (mat == 0) ? Wq : (mat == 1) ? Wk : Wv;
        float s = 0.f;
#pragma unroll
        for (int e = 0; e < 16; e++) s += W[e * 16 + d];
        sWs[t] = (mat == 0) ? s * 0.70710678118654752f : s;
    }
    // stage TE tables: 4 tables x 24 rows x 4 float4 = 384 chunks over 256 lanes
#pragma unroll
    for (int p = 0; p < 2; p++) {
        int idx = t + p * 256;
        if (idx < 384) {
            int tab = idx / 96, rr4 = idx - tab * 96;
            int rr = rr4 >> 2, j = rr4 & 3;
            int row = rbase + rr;
            if (row < NB * LL) {
                const float* src = (tab == 0) ? TEQ : (tab == 1) ? TEK : (tab == 2) ? TEV : TEO;
                reinterpret_cast<float4*>(&sT[tab][rr][0])[j] =
                    reinterpret_cast<const float4*>(src + row * 16)[j];
            }
        }
    }
    __syncthreads();

    // ---- stage B: lanes (g,h), ALL 256 lanes (g=0..31, h=0..7) ----
    {
        int g = t >> 3, h = t & 7;
        int bn = bn0 + g;
        int b = bn / NN;
        int lb = (b - b0) * LL;
        float f[12];
        {
            const float4* fr = reinterpret_cast<const float4*>(flow + bn * LL);
            float4 f0 = fr[0], f1 = fr[1], f2 = fr[2];
            f[0] = f0.x; f[1] = f0.y; f[2] = f0.z; f[3] = f0.w;
            f[4] = f1.x; f[5] = f1.y; f[6] = f1.z; f[7] = f1.w;
            f[8] = f2.x; f[9] = f2.y; f[10] = f2.z; f[11] = f2.w;
        }
        float wqx = sWs[2 * h], wqy = sWs[2 * h + 1];
        float wkx = sWs[16 + 2 * h], wky = sWs[16 + 2 * h + 1];
        float wvx = sWs[32 + 2 * h], wvy = sWs[32 + 2 * h + 1];
        float kx[12], ky[12], vx[12], vy[12];
#pragma unroll
        for (int m = 0; m < LL; m++) {
            float2 tk = *reinterpret_cast<const float2*>(&sT[1][lb + m][2 * h]);
            float2 tv = *reinterpret_cast<const float2*>(&sT[2][lb + m][2 * h]);
            kx[m] = tk.x + f[m] * wkx; ky[m] = tk.y + f[m] * wky;
            vx[m] = tv.x + f[m] * wvx; vy[m] = tv.y + f[m] * wvy;
        }
#pragma unroll
        for (int l = 0; l < LL; l++) {
            float2 tq = *reinterpret_cast<const float2*>(&sT[0][lb + l][2 * h]);
            float qx = tq.x + f[l] * wqx, qy = tq.y + f[l] * wqy;
            float s[12];
            float sum = 0.f;
#pragma unroll
            for (int m = 0; m < LL; m++) {
                s[m] = __expf(qx * kx[m] + qy * ky[m]);  // 1/sqrt2 folded into q
                sum += s[m];
            }
            float a0 = 0.f, a1 = 0.f;
#pragma unroll
            for (int m = 0; m < LL; m++) { a0 += s[m] * vx[m]; a1 += s[m] * vy[m]; }
            float inv = 1.f / sum;
            __half2 hp = __floats2half2_rn(a0 * inv, a1 * inv);
            sA[g][l][h] = *reinterpret_cast<unsigned*>(&hp);
        }
    }
    __syncthreads();

    // ---- stage C: 384 jobs (g,l) over 256 lanes, 2 passes ----
#pragma unroll
    for (int p = 0; p < 2; p++) {
        int jb = t + p * 256;
        if (jb < AGRP * LL) {
            int g = jb / LL, l = jb - g * LL;
            int bn = bn0 + g;
            int b = bn / NN;
            int lb = (b - b0) * LL;
            float f = flow[bn * LL + l];
            float att[16];
            {
                const unsigned* ap = &sA[g][l][0];
                uint2 q0 = *reinterpret_cast<const uint2*>(ap);
                uint2 q1 = *reinterpret_cast<const uint2*>(ap + 2);
                uint2 q2 = *reinterpret_cast<const uint2*>(ap + 4);
                uint2 q3 = *reinterpret_cast<const uint2*>(ap + 6);
                unsigned uu[8] = {q0.x, q0.y, q1.x, q1.y, q2.x, q2.y, q3.x, q3.y};
#pragma unroll
                for (int i = 0; i < 8; i++) {
                    __half2 h = *reinterpret_cast<__half2*>(&uu[i]);
                    float2 fo = __half22float2(h);
                    att[2 * i] = fo.x; att[2 * i + 1] = fo.y;
                }
            }
            float o[16];
            const float4* to4 = reinterpret_cast<const float4*>(&sT[3][lb + l][0]);
#pragma unroll
            for (int j = 0; j < 4; j++) {
                float4 a = to4[j];
                o[4 * j] = a.x; o[4 * j + 1] = a.y; o[4 * j + 2] = a.z; o[4 * j + 3] = a.w;
            }
#pragma unroll
            for (int e = 0; e < 16; e++) {
                float ae = att[e];
                const float4* wo = reinterpret_cast<const float4*>(&sWo[e * 16]);
#pragma unroll
                for (int j = 0; j < 4; j++) {
                    float4 w = wo[j];
                    o[4 * j] += ae * w.x; o[4 * j + 1] += ae * w.y;
                    o[4 * j + 2] += ae * w.z; o[4 * j + 3] += ae * w.w;
                }
            }
            unsigned pk[8];
#pragma unroll
            for (int j = 0; j < 8; j++) {
                unsigned u0 = __float_as_uint(o[2 * j] + f) + 0x8000u;
                unsigned u1 = __float_as_uint(o[2 * j + 1] + f) + 0x8000u;
                pk[j] = (u0 >> 16) | (u1 & 0xffff0000u);
            }
            uint4* dst = reinterpret_cast<uint4*>(xtcn + (size_t)bn * 192 + l * 16);
            uint4 d0; d0.x = pk[0]; d0.y = pk[1]; d0.z = pk[2]; d0.w = pk[3];
            uint4 d1; d1.x = pk[4]; d1.y = pk[5]; d1.z = pk[6]; d1.w = pk[7];
            dst[0] = d0; dst[1] = d1;
        }
    }
}

// ---------------------------------------------------------------------------
// K5 v9 (R4, kept): SINGLE-STAGE fused graph-mix + MLP. One lane owns one
// (b,n,l): private y[16] gather, stream c=0..31 into h1[8], then out.
// ---------------------------------------------------------------------------
__global__ __launch_bounds__(192) void final_kernel(
    const unsigned short* __restrict__ xtcn, const float* __restrict__ G1,
    const float* __restrict__ Wg, const float* __restrict__ Wt,
    const float* __restrict__ bg, const float* __restrict__ W1,
    const float* __restrict__ b1, const float* __restrict__ W2,
    const float* __restrict__ b2, const int* __restrict__ ncnt,
    const int* __restrict__ nidx, const float* __restrict__ nw,
    float* __restrict__ out) {
    __shared__ __align__(16) float sWtT[512];   // [c][d] transposed Wt
    __shared__ __align__(16) float sW1[256];    // [c][o]
    __shared__ __align__(16) float sWg[32];
    __shared__ __align__(16) float sBg[32];
    __shared__ __align__(16) float sB1[8];
    __shared__ __align__(16) float sW2[8];
    __shared__ __align__(16) float sNw[64];
    __shared__ int sNidx[64];

    const int t = threadIdx.x;
    const int bx = blockIdx.x;       // batch group of 16 (XCD = bx%8)
    const int n  = blockIdx.y;       // vertex
    const int b16 = t / LL, l = t - b16 * LL;   // lane = (batch-slot, l)
    const int b = bx * 16 + b16;

    // independent global reads issued early (hide latency under staging)
    const float g = G1[((size_t)b * NN + n) * LL + l];
    const float vb2 = b2[n];
    const int cnt = ncnt[n];

    // ---- stage weights (one pass; all ranges < 192) ----
    // WtT[c*16+d] = Wt[d*32+c]
    sWtT[t]       = Wt[(t & 15) * 32 + (t >> 4)];
    { int i2 = t + 192; sWtT[i2] = Wt[(i2 & 15) * 32 + (i2 >> 4)]; }
    if (t < 128) { int i3 = t + 384; sWtT[i3] = Wt[(i3 & 15) * 32 + (i3 >> 4)]; }
    sW1[t] = W1[n * 256 + t];
    if (t < 64) sW1[t + 192] = W1[n * 256 + t + 192];
    if (t < 64) { sNidx[t] = nidx[n * NBRCAP + t]; sNw[t] = nw[n * NBRCAP + t]; }
    else if (t < 96)  sWg[t - 64] = Wg[t - 64];
    else if (t < 128) sBg[t - 96] = bg[t - 96];
    else if (t < 136) sB1[t - 128] = b1[n * 8 + (t - 128)];
    else if (t < 144) sW2[t - 136] = W2[n * 8 + (t - 136)];
    __syncthreads();

    // ---- private gather: y[16] = sum_i nw[i] * xtcn[b, nidx[i], l, :] ----
    float y[16];
#pragma unroll
    for (int d = 0; d < 16; d++) y[d] = 0.f;
    {
        const unsigned short* bl = xtcn + (size_t)b * (NN * 192) + l * 16;
        for (int i = 0; i < cnt; i++) {
            int m = sNidx[i];             // broadcast LDS read
            float w = sNw[i];             // broadcast LDS read
            const uint4* p = reinterpret_cast<const uint4*>(bl + (size_t)m * 192);
            uint4 u0 = p[0], u1 = p[1];
            y[0]  += w * bf_lo(u0.x); y[1]  += w * bf_hi(u0.x);
            y[2]  += w * bf_lo(u0.y); y[3]  += w * bf_hi(u0.y);
            y[4]  += w * bf_lo(u0.z); y[5]  += w * bf_hi(u0.z);
            y[6]  += w * bf_lo(u0.w); y[7]  += w * bf_hi(u0.w);
            y[8]  += w * bf_lo(u1.x); y[9]  += w * bf_hi(u1.x);
            y[10] += w * bf_lo(u1.y); y[11] += w * bf_hi(u1.y);
            y[12] += w * bf_lo(u1.z); y[13] += w * bf_hi(u1.z);
            y[14] += w * bf_lo(u1.w); y[15] += w * bf_hi(u1.w);
        }
    }

    // ---- fused hid -> h1: h1[o] = b1[o] + sum_c relu(hid_c) * W1[c][o] ----
    float h1[8];
    {
        const float4* b14 = reinterpret_cast<const float4*>(sB1);
        float4 ba = b14[0], bb = b14[1];
        h1[0] = ba.x; h1[1] = ba.y; h1[2] = ba.z; h1[3] = ba.w;
        h1[4] = bb.x; h1[5] = bb.y; h1[6] = bb.z; h1[7] = bb.w;
    }
#pragma unroll
    for (int c = 0; c < 32; c++) {
        const float4* wt = reinterpret_cast<const float4*>(&sWtT[c * 16]);
        float4 w0 = wt[0], w1 = wt[1], w2 = wt[2], w3 = wt[3];
        float hc = sBg[c] + g * sWg[c];
        hc += y[0] * w0.x + y[1] * w0.y + y[2]  * w0.z + y[3]  * w0.w;
        hc += y[4] * w1.x + y[5] * w1.y + y[6]  * w1.z + y[7]  * w1.w;
        hc += y[8] * w2.x + y[9] * w2.y + y[10] * w2.z + y[11] * w2.w;
        hc += y[12] * w3.x + y[13] * w3.y + y[14] * w3.z + y[15] * w3.w;
        hc = fmaxf(hc, 0.f);
        const float4* wr = reinterpret_cast<const float4*>(&sW1[c * 8]);
        float4 a = wr[0], bq4 = wr[1];
        h1[0] += hc * a.x;   h1[1] += hc * a.y;
        h1[2] += hc * a.z;   h1[3] += hc * a.w;
        h1[4] += hc * bq4.x; h1[5] += hc * bq4.y;
        h1[6] += hc * bq4.z; h1[7] += hc * bq4.w;
    }

    // ---- out = sum_o relu(h1[o]) * W2[o] + b2 ----
    float acc = vb2;
    {
        const float4* w24 = reinterpret_cast<const float4*>(sW2);
        float4 wa = w24[0], wb = w24[1];
        acc += fmaxf(h1[0], 0.f) * wa.x + fmaxf(h1[1], 0.f) * wa.y
             + fmaxf(h1[2], 0.f) * wa.z + fmaxf(h1[3], 0.f) * wa.w
             + fmaxf(h1[4], 0.f) * wb.x + fmaxf(h1[5], 0.f) * wb.y
             + fmaxf(h1[6], 0.f) * wb.z + fmaxf(h1[7], 0.f) * wb.w;
    }
    out[((size_t)b * NN + n) * LL + l] = acc;
}

// ---------------------------------------------------------------------------
extern "C" void kernel_launch(void* const* d_in, const int* in_sizes, int n_in,
                              void* d_out, int out_size, void* d_ws, size_t ws_size,
                              hipStream_t stream) {
    const float* flow = (const float*)d_in[0];
    const int* dayc   = (const int*)d_in[1];
    const int* weekc  = (const int*)d_in[2];
    const float* adj  = (const float*)d_in[3];
    const float* demb = (const float*)d_in[4];
    const float* wemb = (const float*)d_in[5];
    const float* Wq = (const float*)d_in[6];  const float* bq = (const float*)d_in[7];
    const float* Wk = (const float*)d_in[8];  const float* bk = (const float*)d_in[9];
    const float* Wv = (const float*)d_in[10]; const float* bv = (const float*)d_in[11];
    const float* Wo = (const float*)d_in[12]; const float* bo = (const float*)d_in[13];
    const float* Wg = (const float*)d_in[14]; const float* Wt = (const float*)d_in[15];
    const float* bg = (const float*)d_in[16];
    const float* W1 = (const float*)d_in[17]; const float* b1 = (const float*)d_in[18];
    const float* W2 = (const float*)d_in[19]; const float* b2 = (const float*)d_in[20];
    float* out = (float*)d_out;
    float* ws  = (float*)d_ws;

    unsigned short* xtcn = (unsigned short*)(ws + 0);   // bf16 region
    float* TEK  = ws + OFF_TEK;   // upper half of xtcn float region
    float* G1   = ws + OFF_G1;
    float* AdT  = ws + OFF_ADT;
    float* TEQ  = ws + OFF_TEQ;
    float* TEV  = ws + OFF_TEV;
    float* TEO  = ws + OFF_TEO;
    float* his  = ws + OFF_HIS;
    float* nw   = ws + OFF_NW;
    int*   nidx = (int*)(ws + OFF_NIDX);
    int*   ncnt = (int*)(ws + OFF_NCNT);

    prep_kernel<<<821, 256, 0, stream>>>(flow, dayc, weekc, demb, wemb,
                                         Wq, bq, Wk, bk, Wv, bv, bo, adj,
                                         his, TEQ, TEK, TEV, TEO, ncnt, nidx, nw);
    adyn_kernel<<<NN, 256, 0, stream>>>(his, AdT);
    attn_g1_kernel<<<G1BLK + ATTNBLK, 256, 0, stream>>>(flow, TEQ, TEK, TEV, TEO,
                                                        Wq, Wk, Wv, Wo, AdT, G1, xtcn);
    final_kernel<<<dim3(16, NN), 192, 0, stream>>>(xtcn, G1, Wg, Wt, bg, W1, b1, W2, b2,
                                                   ncnt, nidx, nw, out);
}

// Round 9
// 245.542 us; speedup vs baseline: 1.0188x; 1.0188x over previous
//
#include <hip/hip_runtime.h>
#include <hip/hip_bf16.h>
#include <hip/hip_fp16.h>
#include <math.h>

// ---- problem constants ----
#define NB 256      // batch
#define NN 307      // vertices
#define NBN 78592   // NB*NN
#define LL 12       // sequence length
#define DDIM 16     // model dim
#define HISW 268    // 267 history cols + 1 zero pad (for float4)
#define HIS4 67     // HISW/4
#define NBRCAP 64   // per-row neighbor capacity (mean 9.2, 64 is ~18 sigma)
#define AGRP 32     // bn rows per 256-thread attn block
#define ADTS 308    // AdT row stride (padded even for float2 alignment)

// ---- workspace layout (float offsets; every segment 16B-aligned) ----
#define OFF_XTCN 0u            // 15089664 ushorts [B,N,L,D] bf16 (=7544832 floats)
#define OFF_TEK  7544832u      //    49152 floats  te@Wk+bk (inside xtcn region)
#define OFF_G1   15089664u     //   943104 floats  [B,N,L]
#define OFF_ADT  16032768u     //    94688 floats  A_dyn^T [m][308]
#define OFF_TEQ  16127456u     //    49152 floats  [B,L,16]  (te@Wq+bq)/sqrt2
#define OFF_HIS  16176608u     //    82288 floats  [N,268]
#define OFF_NW   16258896u     //    19648 floats  nbr weights [N,64]
#define OFF_NIDX 16278544u     //    19648 ints    nbr indices [N,64]
#define OFF_NCNT 16298192u     //      320 ints    nbr counts
#define OFF_TEV  16298512u     //    49152 floats  te@Wv+bv
#define OFF_TEO  16347664u     //    49152 floats  te+bo

__device__ inline float4 mkf4(float a, float b, float c, float d) {
    float4 r; r.x = a; r.y = b; r.z = c; r.w = d; return r;
}
__device__ inline float bf_lo(unsigned u) { return __uint_as_float(u << 16); }
__device__ inline float bf_hi(unsigned u) { return __uint_as_float(u & 0xffff0000u); }

// ---------------------------------------------------------------------------
// K0 fused prep (block-specialized): his | TE tables | sparse A_st rows.
// ---------------------------------------------------------------------------
__global__ __launch_bounds__(256) void prep_kernel(
    const float* __restrict__ flow,
    const int* __restrict__ dayc, const int* __restrict__ weekc,
    const float* __restrict__ demb, const float* __restrict__ wemb,
    const float* __restrict__ Wq, const float* __restrict__ bq,
    const float* __restrict__ Wk, const float* __restrict__ bk,
    const float* __restrict__ Wv, const float* __restrict__ bv,
    const float* __restrict__ bo, const float* __restrict__ adj,
    float* __restrict__ his,
    float* __restrict__ TEQ, float* __restrict__ TEK,
    float* __restrict__ TEV, float* __restrict__ TEO,
    int* __restrict__ ncnt, int* __restrict__ nidx, float* __restrict__ nw) {
    __shared__ float sTE[16][16];
    int bx = blockIdx.x, t = threadIdx.x;
    if (bx < 322) {
        int e = bx * 256 + t;
        if (e < NN * HISW) {
            int n = e / HISW, j = e - n * HISW;
            float v = 0.f;
            if (j < LL) v = flow[n * LL + j];
            else if (j < 267) v = flow[((j - 11) * NN + n) * LL + 11];
            his[e] = v;
        }
    } else if (bx < 514) {
        int r = t >> 4, d = t & 15;
        int row = (bx - 322) * 16 + r;        // < 3072
        int b = row / LL, l = row - b * LL;
        int dc = dayc[b * LL + l], wc = weekc[b * LL + l];
        int i = d >> 1;
        float ang = (float)l * powf(10000.f, -0.125f * (float)i);
        float pe = (d & 1) ? cosf(ang) : sinf(ang);
        float te = demb[dc * DDIM + d] + wemb[wc * DDIM + d] + pe;
        sTE[r][d] = te;
        __syncthreads();
        float aq = bq[d], ak = bk[d], av = bv[d];
#pragma unroll
        for (int e = 0; e < 16; e++) {
            float x = sTE[r][e];
            aq += x * Wq[e * 16 + d];
            ak += x * Wk[e * 16 + d];
            av += x * Wv[e * 16 + d];
        }
        TEQ[row * 16 + d] = aq * 0.70710678118654752f;
        TEK[row * 16 + d] = ak;
        TEV[row * 16 + d] = av;
        TEO[row * 16 + d] = te + bo[d];
    } else {
        if (t < 64) {
            int n = bx - 514;
            float rs = 0.f;
            for (int m0 = 0; m0 < NN; m0 += 64) {
                int m = m0 + t;
                if (m < NN) rs += adj[n * NN + m];
            }
            for (int off = 32; off > 0; off >>= 1) rs += __shfl_xor(rs, off);
            float inv = 1.f / (rs + 1.f);
            int c = 0;
            for (int m0 = 0; m0 < NN; m0 += 64) {
                int m = m0 + t;
                float a = (m < NN) ? adj[n * NN + m] : 0.f;
                bool p = (a != 0.f);
                unsigned long long mask = __ballot(p);
                int pos = __popcll(mask & ((1ull << t) - 1ull));
                if (p && (c + pos) < NBRCAP) {
                    nidx[n * NBRCAP + c + pos] = m;
                    nw[n * NBRCAP + c + pos] = a * inv;
                }
                c += (int)__popcll(mask);
            }
            if (t == 0) ncnt[n] = c < NBRCAP ? c : NBRCAP;
        }
    }
}

// ---------------------------------------------------------------------------
// K1: A_dyn row-softmax of -dist, stored transposed AdT[m*308+n]
// ---------------------------------------------------------------------------
__global__ __launch_bounds__(256) void adyn_kernel(const float* __restrict__ his,
                                                   float* __restrict__ AdT) {
    __shared__ float4 sh[HIS4];
    __shared__ float red[256];
    int n = blockIdx.x, t = threadIdx.x;
    if (t < HIS4) sh[t] = reinterpret_cast<const float4*>(his)[n * HIS4 + t];
    __syncthreads();

    float e0 = 0.f, e1 = 0.f, lsum = 0.f;
    {
        const float4* row = reinterpret_cast<const float4*>(his) + t * HIS4;
        float4 acc = mkf4(0.f, 0.f, 0.f, 0.f);
        for (int j = 0; j < HIS4; j++) {
            float4 a = sh[j], b = row[j];
            float dx = a.x - b.x, dy = a.y - b.y, dz = a.z - b.z, dw = a.w - b.w;
            acc.x += dx * dx; acc.y += dy * dy; acc.z += dz * dz; acc.w += dw * dw;
        }
        float d2 = (acc.x + acc.y) + (acc.z + acc.w);
        e0 = __expf(-sqrtf(fmaxf(d2, 0.f)));
        lsum += e0;
    }
    int m1 = t + 256;
    if (m1 < NN) {
        const float4* row = reinterpret_cast<const float4*>(his) + m1 * HIS4;
        float4 acc = mkf4(0.f, 0.f, 0.f, 0.f);
        for (int j = 0; j < HIS4; j++) {
            float4 a = sh[j], b = row[j];
            float dx = a.x - b.x, dy = a.y - b.y, dz = a.z - b.z, dw = a.w - b.w;
            acc.x += dx * dx; acc.y += dy * dy; acc.z += dz * dz; acc.w += dw * dw;
        }
        float d2 = (acc.x + acc.y) + (acc.z + acc.w);
        e1 = __expf(-sqrtf(fmaxf(d2, 0.f)));
        lsum += e1;
    }
    red[t] = lsum;
    __syncthreads();
    for (int s = 128; s > 0; s >>= 1) {
        if (t < s) red[t] += red[t + s];
        __syncthreads();
    }
    float inv = 1.f / red[0];
    AdT[t * ADTS + n] = e0 * inv;
    if (m1 < NN) AdT[m1 * ADTS + n] = e1 * inv;
}

// ---------------------------------------------------------------------------
// K3 v10 (reinstated standalone; R8 merge reverted — merged kernel ran 90us
// ≈ serial sum because block dispatch order serializes the two phases).
// half2-packed sA: LDS 23KB -> 7 blocks/CU paper.
// ---------------------------------------------------------------------------
__global__ __launch_bounds__(256, 8) void attn_kernel(
    const float* __restrict__ flow,
    const float* __restrict__ TEQ, const float* __restrict__ TEK,
    const float* __restrict__ TEV, const float* __restrict__ TEO,
    const float* __restrict__ Wq, const float* __restrict__ Wk,
    const float* __restrict__ Wv, const float* __restrict__ Wo,
    unsigned short* __restrict__ xtcn) {
    __shared__ __align__(16) float sWo[256];
    __shared__ __align__(16) float sWs[48];        // wq1/sqrt2, wk1, wv1 col-sums
    __shared__ __align__(16) float sT[4][24][16];  // TEQ/TEK/TEV/TEO, 2 b's
    __shared__ __align__(8) unsigned sA[AGRP][LL][10];  // half2-packed att

    const int t = threadIdx.x;
    const int bn0 = blockIdx.x * AGRP;
    const int b0 = bn0 / NN;
    const int rbase = b0 * LL;

    sWo[t] = Wo[t];
    if (t < 48) {
        int mat = t >> 4, d = t & 15;
        const float* W = (mat == 0) ? Wq : (mat == 1) ? Wk : Wv;
        float s = 0.f;
#pragma unroll
        for (int e = 0; e < 16; e++) s += W[e * 16 + d];
        sWs[t] = (mat == 0) ? s * 0.70710678118654752f : s;
    }
    // stage TE tables: 4 tables x 24 rows x 4 float4 = 384 chunks over 256 lanes
#pragma unroll
    for (int p = 0; p < 2; p++) {
        int idx = t + p * 256;
        if (idx < 384) {
            int tab = idx / 96, rr4 = idx - tab * 96;
            int rr = rr4 >> 2, j = rr4 & 3;
            int row = rbase + rr;
            if (row < NB * LL) {
                const float* src = (tab == 0) ? TEQ : (tab == 1) ? TEK : (tab == 2) ? TEV : TEO;
                reinterpret_cast<float4*>(&sT[tab][rr][0])[j] =
                    reinterpret_cast<const float4*>(src + row * 16)[j];
            }
        }
    }
    __syncthreads();

    // ---- stage B: lanes (g,h), ALL 256 lanes (g=0..31, h=0..7) ----
    {
        int g = t >> 3, h = t & 7;
        int bn = bn0 + g;
        int b = bn / NN;
        int lb = (b - b0) * LL;
        float f[12];
        {
            const float4* fr = reinterpret_cast<const float4*>(flow + bn * LL);
            float4 f0 = fr[0], f1 = fr[1], f2 = fr[2];
            f[0] = f0.x; f[1] = f0.y; f[2] = f0.z; f[3] = f0.w;
            f[4] = f1.x; f[5] = f1.y; f[6] = f1.z; f[7] = f1.w;
            f[8] = f2.x; f[9] = f2.y; f[10] = f2.z; f[11] = f2.w;
        }
        float wqx = sWs[2 * h], wqy = sWs[2 * h + 1];
        float wkx = sWs[16 + 2 * h], wky = sWs[16 + 2 * h + 1];
        float wvx = sWs[32 + 2 * h], wvy = sWs[32 + 2 * h + 1];
        float kx[12], ky[12], vx[12], vy[12];
#pragma unroll
        for (int m = 0; m < LL; m++) {
            float2 tk = *reinterpret_cast<const float2*>(&sT[1][lb + m][2 * h]);
            float2 tv = *reinterpret_cast<const float2*>(&sT[2][lb + m][2 * h]);
            kx[m] = tk.x + f[m] * wkx; ky[m] = tk.y + f[m] * wky;
            vx[m] = tv.x + f[m] * wvx; vy[m] = tv.y + f[m] * wvy;
        }
#pragma unroll
        for (int l = 0; l < LL; l++) {
            float2 tq = *reinterpret_cast<const float2*>(&sT[0][lb + l][2 * h]);
            float qx = tq.x + f[l] * wqx, qy = tq.y + f[l] * wqy;
            float s[12];
            float sum = 0.f;
#pragma unroll
            for (int m = 0; m < LL; m++) {
                s[m] = __expf(qx * kx[m] + qy * ky[m]);  // 1/sqrt2 folded into q
                sum += s[m];
            }
            float a0 = 0.f, a1 = 0.f;
#pragma unroll
            for (int m = 0; m < LL; m++) { a0 += s[m] * vx[m]; a1 += s[m] * vy[m]; }
            float inv = 1.f / sum;
            __half2 hp = __floats2half2_rn(a0 * inv, a1 * inv);
            sA[g][l][h] = *reinterpret_cast<unsigned*>(&hp);
        }
    }
    __syncthreads();

    // ---- stage C: 384 jobs (g,l) over 256 lanes, 2 passes ----
#pragma unroll
    for (int p = 0; p < 2; p++) {
        int jb = t + p * 256;
        if (jb < AGRP * LL) {
            int g = jb / LL, l = jb - g * LL;
            int bn = bn0 + g;
            int b = bn / NN;
            int lb = (b - b0) * LL;
            float f = flow[bn * LL + l];
            float att[16];
            {
                const unsigned* ap = &sA[g][l][0];
                uint2 q0 = *reinterpret_cast<const uint2*>(ap);
                uint2 q1 = *reinterpret_cast<const uint2*>(ap + 2);
                uint2 q2 = *reinterpret_cast<const uint2*>(ap + 4);
                uint2 q3 = *reinterpret_cast<const uint2*>(ap + 6);
                unsigned uu[8] = {q0.x, q0.y, q1.x, q1.y, q2.x, q2.y, q3.x, q3.y};
#pragma unroll
                for (int i = 0; i < 8; i++) {
                    __half2 h = *reinterpret_cast<__half2*>(&uu[i]);
                    float2 fo = __half22float2(h);
                    att[2 * i] = fo.x; att[2 * i + 1] = fo.y;
                }
            }
            float o[16];
            const float4* to4 = reinterpret_cast<const float4*>(&sT[3][lb + l][0]);
#pragma unroll
            for (int j = 0; j < 4; j++) {
                float4 a = to4[j];
                o[4 * j] = a.x; o[4 * j + 1] = a.y; o[4 * j + 2] = a.z; o[4 * j + 3] = a.w;
            }
#pragma unroll
            for (int e = 0; e < 16; e++) {
                float ae = att[e];
                const float4* wo = reinterpret_cast<const float4*>(&sWo[e * 16]);
#pragma unroll
                for (int j = 0; j < 4; j++) {
                    float4 w = wo[j];
                    o[4 * j] += ae * w.x; o[4 * j + 1] += ae * w.y;
                    o[4 * j + 2] += ae * w.z; o[4 * j + 3] += ae * w.w;
                }
            }
            unsigned pk[8];
#pragma unroll
            for (int j = 0; j < 8; j++) {
                unsigned u0 = __float_as_uint(o[2 * j] + f) + 0x8000u;
                unsigned u1 = __float_as_uint(o[2 * j + 1] + f) + 0x8000u;
                pk[j] = (u0 >> 16) | (u1 & 0xffff0000u);
            }
            uint4* dst = reinterpret_cast<uint4*>(xtcn + (size_t)bn * 192 + l * 16);
            uint4 d0; d0.x = pk[0]; d0.y = pk[1]; d0.z = pk[2]; d0.w = pk[3];
            uint4 d1; d1.x = pk[4]; d1.y = pk[5]; d1.z = pk[6]; d1.w = pk[7];
            dst[0] = d0; dst[1] = d1;
        }
    }
}

// ---------------------------------------------------------------------------
// K4 v5: G1 = A_dyn @ flow[b], grid (256 b, 5 n-tiles) — standalone again.
// ---------------------------------------------------------------------------
__global__ __launch_bounds__(256) void g1_kernel(const float* __restrict__ flow,
                                                 const float* __restrict__ AdT,
                                                 float* __restrict__ G1) {
    int b = blockIdx.x, nt = blockIdx.y, t = threadIdx.x;
    int lane = t & 63;
    int l0 = (t >> 6) * 3;
    int l0u = __builtin_amdgcn_readfirstlane(l0);
    int n = nt * 64 + lane;
    const float* fb = flow + (size_t)b * (NN * LL);
    const float* ac = AdT + nt * 64 + lane;

    float a0 = 0.f, a1 = 0.f, a2 = 0.f;
#pragma unroll 4
    for (int m = 0; m < NN; m++) {
        float w = ac[(size_t)m * ADTS];
        const float* r = fb + m * LL + l0u;
        float p0 = r[0], p1 = r[1], p2 = r[2];
        a0 += w * p0; a1 += w * p1; a2 += w * p2;
    }
    if (n < NN) {
        float* d = G1 + ((size_t)b * NN + n) * LL + l0;
        d[0] = a0; d[1] = a1; d[2] = a2;
    }
}

// ---------------------------------------------------------------------------
// K5 v9: SINGLE-STAGE fused graph-mix + MLP. One lane owns one (b,n,l).
// ---------------------------------------------------------------------------
__global__ __launch_bounds__(192) void final_kernel(
    const unsigned short* __restrict__ xtcn, const float* __restrict__ G1,
    const float* __restrict__ Wg, const float* __restrict__ Wt,
    const float* __restrict__ bg, const float* __restrict__ W1,
    const float* __restrict__ b1, const float* __restrict__ W2,
    const float* __restrict__ b2, const int* __restrict__ ncnt,
    const int* __restrict__ nidx, const float* __restrict__ nw,
    float* __restrict__ out) {
    __shared__ __align__(16) float sWtT[512];   // [c][d] transposed Wt
    __shared__ __align__(16) float sW1[256];    // [c][o]
    __shared__ __align__(16) float sWg[32];
    __shared__ __align__(16) float sBg[32];
    __shared__ __align__(16) float sB1[8];
    __shared__ __align__(16) float sW2[8];
    __shared__ __align__(16) float sNw[64];
    __shared__ int sNidx[64];

    const int t = threadIdx.x;
    const int bx = blockIdx.x;       // batch group of 16 (XCD = bx%8)
    const int n  = blockIdx.y;       // vertex
    const int b16 = t / LL, l = t - b16 * LL;   // lane = (batch-slot, l)
    const int b = bx * 16 + b16;

    // independent global reads issued early (hide latency under staging)
    const float g = G1[((size_t)b * NN + n) * LL + l];
    const float vb2 = b2[n];
    const int cnt = ncnt[n];

    // ---- stage weights (one pass; all ranges < 192) ----
    // WtT[c*16+d] = Wt[d*32+c]
    sWtT[t]       = Wt[(t & 15) * 32 + (t >> 4)];
    { int i2 = t + 192; sWtT[i2] = Wt[(i2 & 15) * 32 + (i2 >> 4)]; }
    if (t < 128) { int i3 = t + 384; sWtT[i3] = Wt[(i3 & 15) * 32 + (i3 >> 4)]; }
    sW1[t] = W1[n * 256 + t];
    if (t < 64) sW1[t + 192] = W1[n * 256 + t + 192];
    if (t < 64) { sNidx[t] = nidx[n * NBRCAP + t]; sNw[t] = nw[n * NBRCAP + t]; }
    else if (t < 96)  sWg[t - 64] = Wg[t - 64];
    else if (t < 128) sBg[t - 96] = bg[t - 96];
    else if (t < 136) sB1[t - 128] = b1[n * 8 + (t - 128)];
    else if (t < 144) sW2[t - 136] = W2[n * 8 + (t - 136)];
    __syncthreads();

    // ---- private gather: y[16] = sum_i nw[i] * xtcn[b, nidx[i], l, :] ----
    float y[16];
#pragma unroll
    for (int d = 0; d < 16; d++) y[d] = 0.f;
    {
        const unsigned short* bl = xtcn + (size_t)b * (NN * 192) + l * 16;
        for (int i = 0; i < cnt; i++) {
            int m = sNidx[i];             // broadcast LDS read
            float w = sNw[i];             // broadcast LDS read
            const uint4* p = reinterpret_cast<const uint4*>(bl + (size_t)m * 192);
            uint4 u0 = p[0], u1 = p[1];
            y[0]  += w * bf_lo(u0.x); y[1]  += w * bf_hi(u0.x);
            y[2]  += w * bf_lo(u0.y); y[3]  += w * bf_hi(u0.y);
            y[4]  += w * bf_lo(u0.z); y[5]  += w * bf_hi(u0.z);
            y[6]  += w * bf_lo(u0.w); y[7]  += w * bf_hi(u0.w);
            y[8]  += w * bf_lo(u1.x); y[9]  += w * bf_hi(u1.x);
            y[10] += w * bf_lo(u1.y); y[11] += w * bf_hi(u1.y);
            y[12] += w * bf_lo(u1.z); y[13] += w * bf_hi(u1.z);
            y[14] += w * bf_lo(u1.w); y[15] += w * bf_hi(u1.w);
        }
    }

    // ---- fused hid -> h1: h1[o] = b1[o] + sum_c relu(hid_c) * W1[c][o] ----
    float h1[8];
    {
        const float4* b14 = reinterpret_cast<const float4*>(sB1);
        float4 ba = b14[0], bb = b14[1];
        h1[0] = ba.x; h1[1] = ba.y; h1[2] = ba.z; h1[3] = ba.w;
        h1[4] = bb.x; h1[5] = bb.y; h1[6] = bb.z; h1[7] = bb.w;
    }
#pragma unroll
    for (int c = 0; c < 32; c++) {
        const float4* wt = reinterpret_cast<const float4*>(&sWtT[c * 16]);
        float4 w0 = wt[0], w1 = wt[1], w2 = wt[2], w3 = wt[3];
        float hc = sBg[c] + g * sWg[c];
        hc += y[0] * w0.x + y[1] * w0.y + y[2]  * w0.z + y[3]  * w0.w;
        hc += y[4] * w1.x + y[5] * w1.y + y[6]  * w1.z + y[7]  * w1.w;
        hc += y[8] * w2.x + y[9] * w2.y + y[10] * w2.z + y[11] * w2.w;
        hc += y[12] * w3.x + y[13] * w3.y + y[14] * w3.z + y[15] * w3.w;
        hc = fmaxf(hc, 0.f);
        const float4* wr = reinterpret_cast<const float4*>(&sW1[c * 8]);
        float4 a = wr[0], bq4 = wr[1];
        h1[0] += hc * a.x;   h1[1] += hc * a.y;
        h1[2] += hc * a.z;   h1[3] += hc * a.w;
        h1[4] += hc * bq4.x; h1[5] += hc * bq4.y;
        h1[6] += hc * bq4.z; h1[7] += hc * bq4.w;
    }

    // ---- out = sum_o relu(h1[o]) * W2[o] + b2 ----
    float acc = vb2;
    {
        const float4* w24 = reinterpret_cast<const float4*>(sW2);
        float4 wa = w24[0], wb = w24[1];
        acc += fmaxf(h1[0], 0.f) * wa.x + fmaxf(h1[1], 0.f) * wa.y
             + fmaxf(h1[2], 0.f) * wa.z + fmaxf(h1[3], 0.f) * wa.w
             + fmaxf(h1[4], 0.f) * wb.x + fmaxf(h1[5], 0.f) * wb.y
             + fmaxf(h1[6], 0.f) * wb.z + fmaxf(h1[7], 0.f) * wb.w;
    }
    out[((size_t)b * NN + n) * LL + l] = acc;
}

// ---------------------------------------------------------------------------
extern "C" void kernel_launch(void* const* d_in, const int* in_sizes, int n_in,
                              void* d_out, int out_size, void* d_ws, size_t ws_size,
                              hipStream_t stream) {
    const float* flow = (const float*)d_in[0];
    const int* dayc   = (const int*)d_in[1];
    const int* weekc  = (const int*)d_in[2];
    const float* adj  = (const float*)d_in[3];
    const float* demb = (const float*)d_in[4];
    const float* wemb = (const float*)d_in[5];
    const float* Wq = (const float*)d_in[6];  const float* bq = (const float*)d_in[7];
    const float* Wk = (const float*)d_in[8];  const float* bk = (const float*)d_in[9];
    const float* Wv = (const float*)d_in[10]; const float* bv = (const float*)d_in[11];
    const float* Wo = (const float*)d_in[12]; const float* bo = (const float*)d_in[13];
    const float* Wg = (const float*)d_in[14]; const float* Wt = (const float*)d_in[15];
    const float* bg = (const float*)d_in[16];
    const float* W1 = (const float*)d_in[17]; const float* b1 = (const float*)d_in[18];
    const float* W2 = (const float*)d_in[19]; const float* b2 = (const float*)d_in[20];
    float* out = (float*)d_out;
    float* ws  = (float*)d_ws;

    unsigned short* xtcn = (unsigned short*)(ws + 0);   // bf16 region
    float* TEK  = ws + OFF_TEK;   // upper half of xtcn float region
    float* G1   = ws + OFF_G1;
    float* AdT  = ws + OFF_ADT;
    float* TEQ  = ws + OFF_TEQ;
    float* TEV  = ws + OFF_TEV;
    float* TEO  = ws + OFF_TEO;
    float* his  = ws + OFF_HIS;
    float* nw   = ws + OFF_NW;
    int*   nidx = (int*)(ws + OFF_NIDX);
    int*   ncnt = (int*)(ws + OFF_NCNT);

    prep_kernel<<<821, 256, 0, stream>>>(flow, dayc, weekc, demb, wemb,
                                         Wq, bq, Wk, bk, Wv, bv, bo, adj,
                                         his, TEQ, TEK, TEV, TEO, ncnt, nidx, nw);
    adyn_kernel<<<NN, 256, 0, stream>>>(his, AdT);
    attn_kernel<<<NBN / AGRP, 256, 0, stream>>>(flow, TEQ, TEK, TEV, TEO,
                                                Wq, Wk, Wv, Wo, xtcn);
    g1_kernel<<<dim3(NB, 5), 256, 0, stream>>>(flow, AdT, G1);
    final_kernel<<<dim3(16, NN), 192, 0, stream>>>(xtcn, G1, Wg, Wt, bg, W1, b1, W2, b2,
                                                   ncnt, nidx, nw, out);
}